// Round 3
// baseline (214.179 us; speedup 1.0000x reference)
//
#include <hip/hip_runtime.h>
#include <math.h>

// DynamicHybridRouter via bf16-split MFMA (3-term: xh*wh + xh*wl + xl*wh).
// R9: R8 (counted vmcnt + raw barrier) regressed vs R6 (remainder 57 vs 50us)
// with 4x sched_barrier(0)/chunk = m141's known-toxic full order-pinning; the
// pin between loadX and computeC walled the compute phase off from the issue
// phase. R9 keeps the counted-vmcnt pipeline (kills the per-chunk vmcnt(0)
// HBM-queue-empty bubble, ~900cyc x 16) but pins ONLY at phase boundaries,
// like the verified m201 template:
//   - one sched_barrier between stageB and loadX (keeps the 8 B gl_lds older
//     than the 8 x loads so vmcnt(8) drains exactly B),
//   - pins hugging s_barrier (correctness: stops gl_lds(c+2) hoisting across
//     the barrier into LDS other waves still read; stops compute sinking).
// Compute phase is left entirely to the compiler scheduler.
// Also: last-chunk barrier dropped (gates nothing); wfrag 64x256 -> 256x64
// blocks (latency-bound 512KB read spread over 4x more CUs).
// Numerics identical to R6/R8 (same 3-term split, same accumulation order).

#define NROWS 16384
#define DIM   2048
#define NEXP  64
#define BM    64
#define TPB   256
#define CH    4                  // K-steps per chunk (k-span 128)
#define NCH   (DIM / 32 / CH)    // 16 chunks
#define BUFB  32768              // bytes per staging buffer: CH*8*1024

typedef __attribute__((ext_vector_type(4))) float f32x4;
typedef __attribute__((ext_vector_type(8))) short bf16x8;

#define MFMA __builtin_amdgcn_mfma_f32_16x16x32_bf16

__device__ __forceinline__ void gl_lds16(const void* g, void* l) {
  __builtin_amdgcn_global_load_lds(
      (const __attribute__((address_space(1))) unsigned char*)g,
      (__attribute__((address_space(3))) unsigned char*)l, 16, 0, 0);
}

// ---- prologue: w [64][2048] f32 -> B-frag-ordered bf16 hi/lo in ws ----
// frag slot = (kstep*4 + t), kstep 0..63, t 0..3: 64 lanes x bf16x8.
// lane's frag: w[e=16t+(lane&15)][k = kstep*32 + (lane>>4)*8 + j], j=0..7.
__global__ void wfrag_kernel(const float* __restrict__ gw,
                             unsigned short* __restrict__ wsH,
                             unsigned short* __restrict__ wsL) {
  int slot  = blockIdx.x * 64 + threadIdx.x;    // 0..16383 (256 blocks x 64)
  int lane  = slot & 63;
  int t     = (slot >> 6) & 3;
  int kstep = slot >> 8;
  int e  = 16 * t + (lane & 15);
  int k0 = kstep * 32 + (lane >> 4) * 8;
  const float* src = gw + (size_t)e * DIM + k0;
  bf16x8 vh, vl;
#pragma unroll
  for (int j = 0; j < 8; ++j) {
    float w = src[j];
    unsigned u = __float_as_uint(w);
    vh[j] = (short)(u >> 16);
    float hi = __uint_as_float(u & 0xffff0000u);
    float rl = w - hi;
    vl[j] = (short)(__float_as_uint(rl) >> 16);
  }
  ((bf16x8*)wsH)[slot] = vh;
  ((bf16x8*)wsL)[slot] = vl;
}

// ---- main kernel ----
__global__ __launch_bounds__(TPB, 1)
void router_mfma(const float* __restrict__ x,
                 const unsigned short* __restrict__ wsH,
                 const unsigned short* __restrict__ wsL,
                 const float* __restrict__ gb,
                 const int* __restrict__ mat,
                 float* __restrict__ out) {
  // staging: 2 buffers x CH steps x 8 units(4 tiles x hi/lo) x 1KB = 64KB,
  // reused post-loop as the 64x64 logit slab (16KB in buf0; last chunk c=15
  // computes from buf1 -> no overlap with slab writes).
  __shared__ __align__(16) char lds[2 * BUFB];
  __shared__ float p_a[BM], p_b[BM];
  __shared__ int   p_i[BM], p_j[BM];
  __shared__ int   s_flag;

  const int tid  = threadIdx.x;
  const int wave = tid >> 6;     // row group: rows 16*wave .. +15; stages step st=wave
  const int lane = tid & 63;
  const int m    = lane & 15;
  const int kg   = lane >> 4;
  const int row0 = blockIdx.x * BM;

  if (tid < 64) {
    unsigned long long b = __ballot(mat[lane] == 0);
    if (lane == 0) s_flag = (b != 0ull) ? 1 : 0;
  }

  f32x4 acc[4];
#pragma unroll
  for (int t = 0; t < 4; ++t) acc[t] = (f32x4)0.0f;

  const unsigned char* wsHb = (const unsigned char*)wsH;
  const unsigned char* wsLb = (const unsigned char*)wsL;
  const float* xb = x + (size_t)(row0 + 16 * wave + m) * DIM + kg * 8;

  // wave w stages step st=w of chunk c: 8 units (4 tiles x hi/lo), 1KB each.
  auto stageB = [&](int c) {
    const int par = (c & 1) * BUFB;
#pragma unroll
    for (int u = 0; u < 8; ++u) {
      int t = u >> 1, h = u & 1;
      size_t slot = (size_t)((c * CH + wave) * 4 + t);
      gl_lds16((h ? wsLb : wsHb) + slot * 1024 + (size_t)lane * 16,
               lds + par + (wave * 8 + u) * 1024);
    }
  };
  auto loadX = [&](int c, float4 (&dst)[CH][2]) {
    const float* xp = xb + c * (CH * 32);
#pragma unroll
    for (int st = 0; st < CH; ++st) {
      dst[st][0] = *(const float4*)(xp + st * 32);
      dst[st][1] = *(const float4*)(xp + st * 32 + 4);
    }
  };
  auto computeC = [&](int c, float4 (&cur)[CH][2]) {
    const int par = (c & 1) * BUFB;
#pragma unroll
    for (int st = 0; st < CH; ++st) {
      const char* bb = lds + par + st * 8192 + lane * 16;
      bf16x8 bh[4], bl[4];
#pragma unroll
      for (int t = 0; t < 4; ++t) {
        bh[t] = *(const bf16x8*)(bb + (2 * t) * 1024);
        bl[t] = *(const bf16x8*)(bb + (2 * t + 1) * 1024);
      }
      bf16x8 ah, al;
#pragma unroll
      for (int q = 0; q < 2; ++q) {
        float4 v = cur[st][q];
        float ff[4] = {v.x, v.y, v.z, v.w};
#pragma unroll
        for (int j = 0; j < 4; ++j) {
          unsigned u = __float_as_uint(ff[j]);
          ah[q * 4 + j] = (short)(u >> 16);
          float hi = __uint_as_float(u & 0xffff0000u);
          float rl = ff[j] - hi;
          al[q * 4 + j] = (short)(__float_as_uint(rl) >> 16);
        }
      }
#pragma unroll
      for (int t = 0; t < 4; ++t) {
        acc[t] = MFMA(ah, bh[t], acc[t], 0, 0, 0);
        acc[t] = MFMA(ah, bl[t], acc[t], 0, 0, 0);
        acc[t] = MFMA(al, bh[t], acc[t], 0, 0, 0);
      }
    }
  };

  float4 xA[CH][2], xB[CH][2];

  // ---- prologue: stage chunk 0 (B oldest), x chunk 0, drain B, barrier ----
  stageB(0);
  __builtin_amdgcn_sched_barrier(0);   // keep B older than x
  loadX(0, xA);
  asm volatile("s_waitcnt vmcnt(8)" ::: "memory");  // B(0) in LDS; x(0) rides
  __builtin_amdgcn_sched_barrier(0);
  __builtin_amdgcn_s_barrier();
  __builtin_amdgcn_sched_barrier(0);

  auto body = [&](int c, float4 (&cur)[CH][2], float4 (&nxt)[CH][2]) {
    const bool more = (c + 1 < NCH);
    if (more) {
      stageB(c + 1);                       // 8 gl_lds (oldest outstanding)
      __builtin_amdgcn_sched_barrier(0);   // keep B older than x
      loadX(c + 1, nxt);                   // 8 x dwordx4 (youngest)
    }
    computeC(c, cur);                      // compute phase: compiler-free
    if (more) {
      // drain only the 8 B gl_lds; the 8 x loads ride across the barrier
      asm volatile("s_waitcnt vmcnt(8)" ::: "memory");
      __builtin_amdgcn_sched_barrier(0);   // nothing crosses the barrier
      __builtin_amdgcn_s_barrier();
      __builtin_amdgcn_sched_barrier(0);
    }
    // last chunk: no barrier needed (epilogue slab is in buf0, chunk 15 read
    // buf1; epilogue has its own __syncthreads after slab writes)
  };

#pragma unroll 1
  for (int c = 0; c < NCH; c += 2) {
    body(c, xA, xB);
    body(c + 1, xB, xA);
  }

  // ---- epilogue: slab reuse ----
  // C/D layout: col(lane&15)=expert-in-tile, row=kg*4+reg -> local x-row.
  float* slab = (float*)lds;   // [64 rows][64 experts]
  {
    float gbv[4];
#pragma unroll
    for (int t = 0; t < 4; ++t) gbv[t] = gb[16 * t + m];
#pragma unroll
    for (int t = 0; t < 4; ++t)
#pragma unroll
      for (int reg = 0; reg < 4; ++reg)
        slab[(16 * wave + kg * 4 + reg) * NEXP + 16 * t + m] = acc[t][reg] + gbv[t];
  }
  __syncthreads();

  const int flag = s_flag;

  // per-row routing (threads 0..63; rotated scan spreads LDS banks)
  if (tid < BM) {
    const float* rowp = slab + tid * NEXP;
    if (flag == 0) {
      float m1 = -1e30f, m2 = -1e30f;
      int i1 = 0, i2 = 0;
      for (int ee = 0; ee < NEXP; ++ee) {
        int e = (ee + tid) & (NEXP - 1);
        float v = rowp[e];
        if (v > m1) { m2 = m1; i2 = i1; m1 = v; i1 = e; }
        else if (v > m2) { m2 = v; i2 = e; }
      }
      float t = expf(m2 - m1);
      float pa = 1.0f / (1.0f + t);
      p_a[tid] = pa;
      p_b[tid] = t * pa;
      p_i[tid] = i1;
      p_j[tid] = i2;
    } else {
      float mx = -1e30f;
      for (int ee = 0; ee < NEXP; ++ee)
        mx = fmaxf(mx, rowp[(ee + tid) & (NEXP - 1)]);
      float ssum = 0.0f;
      for (int ee = 0; ee < NEXP; ++ee)
        ssum += expf((rowp[(ee + tid) & (NEXP - 1)] - mx) * 0.5f);  // /T=2
      p_a[tid] = mx;
      p_b[tid] = 1.0f / ssum;
    }
  }
  __syncthreads();

  // output: 64x64 tile = 1024 float4, 4 per thread
#pragma unroll
  for (int i = 0; i < 4; ++i) {
    int q  = tid + i * TPB;
    int r  = q >> 4;
    int e0 = (q & 15) * 4;
    float4 v;
    if (flag == 0) {
      int i1 = p_i[r], i2 = p_j[r];
      float a = p_a[r], b = p_b[r];
      v.x = (e0 + 0 == i1) ? a : (e0 + 0 == i2) ? b : 0.0f;
      v.y = (e0 + 1 == i1) ? a : (e0 + 1 == i2) ? b : 0.0f;
      v.z = (e0 + 2 == i1) ? a : (e0 + 2 == i2) ? b : 0.0f;
      v.w = (e0 + 3 == i1) ? a : (e0 + 3 == i2) ? b : 0.0f;
    } else {
      float mx = p_a[r], inv = p_b[r];
      const float* rowp = slab + r * NEXP + e0;
      v.x = expf((rowp[0] - mx) * 0.5f) * inv;
      v.y = expf((rowp[1] - mx) * 0.5f) * inv;
      v.z = expf((rowp[2] - mx) * 0.5f) * inv;
      v.w = expf((rowp[3] - mx) * 0.5f) * inv;
    }
    *(float4*)(out + (size_t)(row0 + r) * NEXP + e0) = v;
  }
}

extern "C" void kernel_launch(void* const* d_in, const int* in_sizes, int n_in,
                              void* d_out, int out_size, void* d_ws, size_t ws_size,
                              hipStream_t stream) {
  const float* x  = (const float*)d_in[0];
  const float* gw = (const float*)d_in[1];
  const float* gb = (const float*)d_in[2];
  const int*   mt = (const int*)d_in[3];
  float* outp = (float*)d_out;
  (void)in_sizes; (void)n_in; (void)out_size; (void)ws_size;

  unsigned short* wsH = (unsigned short*)d_ws;
  unsigned short* wsL = wsH + 64 * DIM;

  wfrag_kernel<<<256, 64, 0, stream>>>(gw, wsH, wsL);
  router_mfma<<<NROWS / BM, TPB, 0, stream>>>(x, wsH, wsL, gb, mt, outp);
}